// Round 20
// baseline (176.331 us; speedup 1.0000x reference)
//
#include <hip/hip_runtime.h>

typedef __attribute__((ext_vector_type(8))) _Float16 h8;
typedef __attribute__((ext_vector_type(4))) _Float16 h4;
typedef __attribute__((ext_vector_type(4))) float f4;
typedef __attribute__((ext_vector_type(16))) float f16x;
typedef __attribute__((ext_vector_type(4))) unsigned u4;

#define MFMA16(a,b,c) __builtin_amdgcn_mfma_f32_16x16x32_f16(a,b,c,0,0,0)
#define MFMA32(a,b,c) __builtin_amdgcn_mfma_f32_32x32x16_f16(a,b,c,0,0,0)

// async global->LDS, 16B per lane; LDS dest = wave-uniform base + lane*16
__device__ inline void gload16(const void* g, void* l) {
    __builtin_amdgcn_global_load_lds(
        (const __attribute__((address_space(1))) void*)g,
        (__attribute__((address_space(3))) void*)l, 16, 0, 0);
}

// partner-half (lane ^ 32) value, semantics-guaranteed
__device__ inline float swap_half(float x) { return __shfl_xor(x, 32, 64); }

// ---- fused preprocessing: x f32->f16 convert (blocks 0..8191) +
//      weight transposes Wa/Wp fp32 (1024,N) -> f16 (N,1024) (blocks 8192..9215) ----
__global__ __launch_bounds__(256) void k_preproc(const float* __restrict__ x,
                                                 _Float16* __restrict__ xh,
                                                 const float* __restrict__ Wa,
                                                 _Float16* __restrict__ WaT,
                                                 const float* __restrict__ Wp,
                                                 _Float16* __restrict__ WpT) {
    __shared__ float tile[64 * 68];
    const int bid = blockIdx.x;
    const int t = threadIdx.x;
    if (bid < 8192) {                       // convert path: 8192*256*4 = 8M elems
        int i = bid * 256 + t;
        float4 v = ((const float4*)x)[i];
        h4 h;
        h[0] = (_Float16)v.x; h[1] = (_Float16)v.y;
        h[2] = (_Float16)v.z; h[3] = (_Float16)v.w;
        ((h4*)xh)[i] = h;
        return;
    }
    const int t2 = bid - 8192;              // 0..1023 -> (bx 0..15, by 0..63)
    const int bx = t2 & 15, by = t2 >> 4;
    const int K = 1024;
    const bool isA = (by < 48);
    const float* W = isA ? Wa : Wp;
    _Float16* Wt = isA ? WaT : WpT;
    const int N = isA ? 3072 : 1024;
    const int n0 = (isA ? by : (by - 48)) * 64;
    const int k0 = bx * 64;
    const int tr = t >> 4;
    const int tc = t & 15;
#pragma unroll
    for (int i = 0; i < 4; ++i) {
        int r = tr + i * 16;
        float4 v = *(const float4*)(W + (size_t)(k0 + r) * N + n0 + tc * 4);
        *(float4*)(&tile[r * 68 + tc * 4]) = v;
    }
    __syncthreads();
#pragma unroll
    for (int i = 0; i < 4; ++i) {
        int nl = tr + i * 16;
        h4 hv;
#pragma unroll
        for (int j = 0; j < 4; ++j)
            hv[j] = (_Float16)tile[(tc * 4 + j) * 68 + nl];
        *(h4*)(Wt + (size_t)(n0 + nl) * K + k0 + tc * 4) = hv;
    }
}

// ---------------- 128xBN MFMA GEMM, 2-phase double-buffered gload_lds ----------------
// Session-best sync structure (r8/r16/r18 verified); BN=192 QKV (r19 best-total),
// BN=128 proj. MODE 0: scatter Q/K (B,H,T,64), V^T (B,H,64,T); Q pre-scaled
// 0.125*log2(e) (attention works in exp2 domain). MODE 1: fp32 out.
template <int BN, int MODE>
__global__ __launch_bounds__(256) void k_gemm(const _Float16* __restrict__ A,
                                              const _Float16* __restrict__ Bt,
                                              const float* __restrict__ bias,
                                              _Float16* __restrict__ oQ,
                                              _Float16* __restrict__ oK,
                                              _Float16* __restrict__ oV,
                                              float* __restrict__ oF,
                                              int M, int N, int K) {
    constexpr int BFR = BN / 32;          // B frag cols per wave
    constexpr int BSI = BN / 64;          // B stage instrs per wave
    __shared__ _Float16 As[2][128 * 32];  // linear [row][k], 64B rows
    __shared__ _Float16 Bs[2][BN * 32];
    const int tid = threadIdx.x;
    const int lane = tid & 63, wv = tid >> 6;
    const int wm = wv >> 1, wn = wv & 1;
    const int l15 = lane & 15, l4 = lane >> 4;
    const int bm = blockIdx.x * 128, bn = blockIdx.y * BN;
    f4 acc[4][BFR] = {};

    const int srow = lane >> 2, scol = (lane & 3) * 8;
    const _Float16* Ag = A + (size_t)(bm + srow) * K + scol;
    const _Float16* Bg = Bt + (size_t)(bn + srow) * K + scol;

#pragma unroll
    for (int j = 0; j < 2; ++j)
        gload16(Ag + (size_t)((wv * 2 + j) * 16) * K, &As[0][(wv * 2 + j) * 512]);
#pragma unroll
    for (int j = 0; j < BSI; ++j)
        gload16(Bg + (size_t)((wv * BSI + j) * 16) * K, &Bs[0][(wv * BSI + j) * 512]);
    asm volatile("s_waitcnt vmcnt(0)" ::: "memory");
    __syncthreads();

    int cur = 0;
    for (int k0 = 0; k0 < K; k0 += 32) {
        if (k0 + 32 < K) {
#pragma unroll
            for (int j = 0; j < 2; ++j)
                gload16(Ag + (size_t)((wv * 2 + j) * 16) * K + k0 + 32,
                        &As[cur ^ 1][(wv * 2 + j) * 512]);
#pragma unroll
            for (int j = 0; j < BSI; ++j)
                gload16(Bg + (size_t)((wv * BSI + j) * 16) * K + k0 + 32,
                        &Bs[cur ^ 1][(wv * BSI + j) * 512]);
        }

        const _Float16* Ac = As[cur];
        const _Float16* Bc = Bs[cur];
        h8 af[4], bf[BFR];
#pragma unroll
        for (int i = 0; i < 4; ++i)
            af[i] = *(const h8*)(&Ac[(wm * 64 + i * 16 + l15) * 32 + l4 * 8]);
#pragma unroll
        for (int i = 0; i < BFR; ++i)
            bf[i] = *(const h8*)(&Bc[(wn * (BN / 2) + i * 16 + l15) * 32 + l4 * 8]);
        __builtin_amdgcn_s_setprio(1);
#pragma unroll
        for (int mi = 0; mi < 4; ++mi)
#pragma unroll
            for (int ni = 0; ni < BFR; ++ni)
                acc[mi][ni] = MFMA16(af[mi], bf[ni], acc[mi][ni]);
        __builtin_amdgcn_s_setprio(0);

        asm volatile("s_waitcnt vmcnt(0)" ::: "memory");
        __syncthreads();
        cur ^= 1;
    }

#pragma unroll
    for (int mi = 0; mi < 4; ++mi) {
#pragma unroll
        for (int ni = 0; ni < BFR; ++ni) {
            int col = bn + wn * (BN / 2) + ni * 16 + l15;
            float bv = bias[col];
            int rb = bm + wm * 64 + mi * 16 + l4 * 4;
            if (MODE == 0) {
                int which = col >> 10, n1 = col & 1023;
                int hh = n1 >> 6, dd = n1 & 63;
                if (which == 2) {
                    int b = rb >> 11, tq = rb & 2047;
                    h4 pv;
#pragma unroll
                    for (int i = 0; i < 4; ++i) pv[i] = (_Float16)(acc[mi][ni][i] + bv);
                    *(h4*)(oV + ((size_t)(b * 16 + hh) * 64 + dd) * 2048 + tq) = pv;
                } else {
                    _Float16* dst = which == 0 ? oQ : oK;
                    const float scl = which == 0 ? 0.18033688011112042f : 1.0f; // 0.125*log2(e)
#pragma unroll
                    for (int i = 0; i < 4; ++i) {
                        int row = rb + i;
                        int b = row >> 11, tq = row & 2047;
                        dst[(((size_t)b * 16 + hh) * 2048 + tq) * 64 + dd] =
                            (_Float16)((acc[mi][ni][i] + bv) * scl);
                    }
                }
            } else {
#pragma unroll
                for (int i = 0; i < 4; ++i)
                    oF[(size_t)(rb + i) * N + col] = acc[mi][ni][i] + bv;
            }
        }
    }
}

// ---------------- causal flash attention: 4 waves x 32 q-rows, shared 64-key K/V tile ----------------
#define SWZI(row, cb) ((((row) << 7) + ((cb) ^ ((((row) & 7) << 4)))) >> 1)

__global__ __launch_bounds__(256) void k_attn(const _Float16* __restrict__ Qh,
                                              const _Float16* __restrict__ Kh,
                                              const _Float16* __restrict__ Vt,
                                              _Float16* __restrict__ Yh) {
    __shared__ _Float16 lds[8192];
    const int bid = blockIdx.x;
    const int bh = bid & 63;
    const int qt = 15 - (bid >> 6);
    const int tid = threadIdx.x, w = tid >> 6;
    const int l31 = tid & 31, hi = (tid >> 5) & 1;
    const int h16 = hi * 16, h4o = hi * 4;
    const size_t base = (size_t)bh * 2048 * 64;

    const int qabs = qt * 128 + w * 32 + l31;
    h8 qf[4];
#pragma unroll
    for (int dk = 0; dk < 4; ++dk)
        qf[dk] = *(const h8*)(Qh + base + (size_t)qabs * 64 + dk * 16 + hi * 8);

    f16x O0 = {}, O1 = {};
    float m = -1e30f, l = 0.f;

    const int sr = tid >> 3;
    const int sc8 = (tid & 7) * 8;
    const int scb = (tid & 7) * 16;
    const int kbb = 2 * qt + 1;
    const int kbw = 2 * qt + (w >> 1);

    {
#pragma unroll
        for (int j = 0; j < 2; ++j) {
            int row = j * 32 + sr;
            h8 kv = *(const h8*)(Kh + base + (size_t)row * 64 + sc8);
            h8 vv = *(const h8*)(Vt + base + (size_t)row * 2048 + sc8);
            *(h8*)(&lds[SWZI(row, scb)]) = kv;
            *(h8*)(&lds[4096 + SWZI(row, scb)]) = vv;
        }
    }
    __syncthreads();

    for (int kb = 0; kb <= kbb; ++kb) {
        const bool pre = (kb < kbb);
        h8 kn[2], vn[2];
        if (pre) {
#pragma unroll
            for (int j = 0; j < 2; ++j) {
                int row = j * 32 + sr;
                kn[j] = *(const h8*)(Kh + base + (size_t)((kb + 1) * 64 + row) * 64 + sc8);
                vn[j] = *(const h8*)(Vt + base + (size_t)row * 2048 + (kb + 1) * 64 + sc8);
            }
        }

        if (kb <= kbw) {
            f16x S0 = {}, S1 = {};
            __builtin_amdgcn_s_setprio(1);
#pragma unroll
            for (int dk = 0; dk < 4; ++dk) {
                h8 kf0 = *(const h8*)(&lds[SWZI(l31, dk * 32 + h16)]);
                h8 kf1 = *(const h8*)(&lds[SWZI(32 + l31, dk * 32 + h16)]);
                S0 = MFMA32(kf0, qf[dk], S0);
                S1 = MFMA32(kf1, qf[dk], S1);
            }
            __builtin_amdgcn_s_setprio(0);

            if (kb == kbw) {
#pragma unroll
                for (int r = 0; r < 16; ++r) {
                    int key = kb * 64 + (r & 3) + 8 * (r >> 2) + h4o;
                    if (key > qabs) S0[r] = -1e30f;
                    if (key + 32 > qabs) S1[r] = -1e30f;
                }
            }

            float tr[16];
#pragma unroll
            for (int r = 0; r < 16; ++r) tr[r] = fmaxf(S0[r], S1[r]);
#pragma unroll
            for (int st = 8; st >= 1; st >>= 1)
#pragma unroll
                for (int r = 0; r < st; ++r) tr[r] = fmaxf(tr[r], tr[r + st]);
            float pm = fmaxf(tr[0], swap_half(tr[0]));
            if (!__all(pm - m <= 8.f)) {
                float mnew = fmaxf(m, pm);
                float scl = __builtin_amdgcn_exp2f(m - mnew);
                m = mnew;
                l *= scl;
#pragma unroll
                for (int r = 0; r < 16; ++r) { O0[r] *= scl; O1[r] *= scl; }
            }
#pragma unroll
            for (int r = 0; r < 16; ++r) {
                S0[r] = __builtin_amdgcn_exp2f(S0[r] - m);
                S1[r] = __builtin_amdgcn_exp2f(S1[r] - m);
            }
#pragma unroll
            for (int r = 0; r < 16; ++r) tr[r] = S0[r] + S1[r];
#pragma unroll
            for (int st = 8; st >= 1; st >>= 1)
#pragma unroll
                for (int r = 0; r < st; ++r) tr[r] += tr[r + st];
            l += tr[0] + swap_half(tr[0]);

            h8 pb[4];
#pragma unroll
            for (int kk = 0; kk < 4; ++kk) {
                const int bb = (kk & 1) * 8;
                unsigned W0, W1, W2, W3;
                if (kk < 2) {
                    W0 = __builtin_bit_cast(unsigned, __builtin_amdgcn_cvt_pkrtz(S0[bb + 0], S0[bb + 1]));
                    W1 = __builtin_bit_cast(unsigned, __builtin_amdgcn_cvt_pkrtz(S0[bb + 2], S0[bb + 3]));
                    W2 = __builtin_bit_cast(unsigned, __builtin_amdgcn_cvt_pkrtz(S0[bb + 4], S0[bb + 5]));
                    W3 = __builtin_bit_cast(unsigned, __builtin_amdgcn_cvt_pkrtz(S0[bb + 6], S0[bb + 7]));
                } else {
                    W0 = __builtin_bit_cast(unsigned, __builtin_amdgcn_cvt_pkrtz(S1[bb + 0], S1[bb + 1]));
                    W1 = __builtin_bit_cast(unsigned, __builtin_amdgcn_cvt_pkrtz(S1[bb + 2], S1[bb + 3]));
                    W2 = __builtin_bit_cast(unsigned, __builtin_amdgcn_cvt_pkrtz(S1[bb + 4], S1[bb + 5]));
                    W3 = __builtin_bit_cast(unsigned, __builtin_amdgcn_cvt_pkrtz(S1[bb + 6], S1[bb + 7]));
                }
                unsigned E0 = (unsigned)__shfl_xor((int)(hi ? W0 : W2), 32, 64);
                unsigned E1 = (unsigned)__shfl_xor((int)(hi ? W1 : W3), 32, 64);
                u4 wvv;
                wvv[0] = hi ? E0 : W0;
                wvv[1] = hi ? E1 : W1;
                wvv[2] = hi ? W2 : E0;
                wvv[3] = hi ? W3 : E1;
                pb[kk] = __builtin_bit_cast(h8, wvv);
            }

            __builtin_amdgcn_s_setprio(1);
#pragma unroll
            for (int kk = 0; kk < 4; ++kk) {
                h8 vf0 = *(const h8*)(&lds[4096 + SWZI(l31, kk * 32 + h16)]);
                h8 vf1 = *(const h8*)(&lds[4096 + SWZI(32 + l31, kk * 32 + h16)]);
                O0 = MFMA32(vf0, pb[kk], O0);
                O1 = MFMA32(vf1, pb[kk], O1);
            }
            __builtin_amdgcn_s_setprio(0);
        }

        __syncthreads();
        if (pre) {
#pragma unroll
            for (int j = 0; j < 2; ++j) {
                int row = j * 32 + sr;
                *(h8*)(&lds[SWZI(row, scb)]) = kn[j];
                *(h8*)(&lds[4096 + SWZI(row, scb)]) = vn[j];
            }
            __syncthreads();
        }
    }

    __syncthreads();

    {
        float inv = 1.0f / l;
        const int R = w * 32 + l31;
#pragma unroll
        for (int rr = 0; rr < 4; ++rr) {
            h4 a, b;
#pragma unroll
            for (int q = 0; q < 4; ++q) {
                a[q] = (_Float16)(O0[rr * 4 + q] * inv);
                b[q] = (_Float16)(O1[rr * 4 + q] * inv);
            }
            *(h4*)(&lds[SWZI(R, rr * 16 + hi * 8)]) = a;
            *(h4*)(&lds[SWZI(R, 64 + rr * 16 + hi * 8)]) = b;
        }
    }
    __syncthreads();
    {
        const int b = bh >> 4, head = bh & 15;
        const int row = tid >> 1;
#pragma unroll
        for (int i = 0; i < 4; ++i) {
            int seg = (tid & 1) * 4 + i;
            h8 v = *(const h8*)(&lds[SWZI(row, seg * 16)]);
            *(h8*)(Yh + ((size_t)(b * 2048 + qt * 128 + row)) * 1024 + head * 64 + seg * 8) = v;
        }
    }
}

extern "C" void kernel_launch(void* const* d_in, const int* in_sizes, int n_in,
                              void* d_out, int out_size, void* d_ws, size_t ws_size,
                              hipStream_t stream) {
    const float* x  = (const float*)d_in[0];
    const float* Wa = (const float*)d_in[1];
    const float* ba = (const float*)d_in[2];
    const float* Wp = (const float*)d_in[3];
    const float* bp = (const float*)d_in[4];
    float* out = (float*)d_out;

    _Float16* ws = (_Float16*)d_ws;
    const size_t SZ_X = (size_t)8192 * 1024;
    const size_t SZ_WA = (size_t)3072 * 1024;
    const size_t SZ_WP = (size_t)1024 * 1024;
    const size_t SZ_H = (size_t)64 * 2048 * 64;
    _Float16* xh  = ws;
    _Float16* WaT = xh + SZ_X;
    _Float16* WpT = WaT + SZ_WA;
    _Float16* Qh  = WpT + SZ_WP;
    _Float16* Kh  = Qh + SZ_H;
    _Float16* Vth = Kh + SZ_H;    // V transposed: (bh, d, t)
    _Float16* Yh  = Vth + SZ_H;

    // fused convert + weight transposes: 8192 convert blocks + 1024 transpose blocks
    k_preproc<<<9216, 256, 0, stream>>>(x, xh, Wa, WaT, Wp, WpT);
    // QKV: 128x192 tiles -> grid 64x16 = 1024, no dispatch tail
    k_gemm<192, 0><<<dim3(64, 16), 256, 0, stream>>>(xh, WaT, ba, Qh, Kh, Vth, nullptr,
                                                     8192, 3072, 1024);
    k_attn<<<1024, 256, 0, stream>>>(Qh, Kh, Vth, Yh);
    k_gemm<128, 1><<<dim3(64, 8), 256, 0, stream>>>(Yh, WpT, bp, nullptr, nullptr, nullptr,
                                                    out, 8192, 1024, 1024);
}

// Round 21
// 175.579 us; speedup vs baseline: 1.0043x; 1.0043x over previous
//
#include <hip/hip_runtime.h>

typedef __attribute__((ext_vector_type(8))) _Float16 h8;
typedef __attribute__((ext_vector_type(4))) _Float16 h4;
typedef __attribute__((ext_vector_type(4))) float f4;
typedef __attribute__((ext_vector_type(16))) float f16x;
typedef __attribute__((ext_vector_type(4))) unsigned u4;

#define MFMA16(a,b,c) __builtin_amdgcn_mfma_f32_16x16x32_f16(a,b,c,0,0,0)
#define MFMA32(a,b,c) __builtin_amdgcn_mfma_f32_32x32x16_f16(a,b,c,0,0,0)

// async global->LDS, 16B per lane; LDS dest = wave-uniform base + lane*16
__device__ inline void gload16(const void* g, void* l) {
    __builtin_amdgcn_global_load_lds(
        (const __attribute__((address_space(1))) void*)g,
        (__attribute__((address_space(3))) void*)l, 16, 0, 0);
}

// partner-half (lane ^ 32) value, semantics-guaranteed
__device__ inline float swap_half(float x) { return __shfl_xor(x, 32, 64); }

// ---------------- fp32 -> f16 elementwise (vectorized) ----------------
__global__ __launch_bounds__(256) void k_f32_to_f16(const float* __restrict__ in,
                                                    _Float16* __restrict__ out, int n4) {
    int i = blockIdx.x * 256 + threadIdx.x;
    if (i < n4) {
        float4 v = ((const float4*)in)[i];
        h4 h;
        h[0] = (_Float16)v.x; h[1] = (_Float16)v.y;
        h[2] = (_Float16)v.z; h[3] = (_Float16)v.w;
        ((h4*)out)[i] = h;
    }
}

// ---- fused weight transposes: fp32 (1024,N)->f16 (N,1024), Wa (N=3072) + Wp (N=1024) ----
__global__ __launch_bounds__(256) void k_transpose_both(const float* __restrict__ Wa,
                                                        _Float16* __restrict__ WaT,
                                                        const float* __restrict__ Wp,
                                                        _Float16* __restrict__ WpT) {
    __shared__ float tile[64 * 68];
    const int K = 1024;
    const bool isA = (blockIdx.y < 48);
    const float* W = isA ? Wa : Wp;
    _Float16* Wt = isA ? WaT : WpT;
    const int N = isA ? 3072 : 1024;
    const int n0 = (isA ? blockIdx.y : (blockIdx.y - 48)) * 64;
    const int k0 = blockIdx.x * 64;
    const int t = threadIdx.x;
    const int tr = t >> 4;
    const int tc = t & 15;
#pragma unroll
    for (int i = 0; i < 4; ++i) {
        int r = tr + i * 16;
        float4 v = *(const float4*)(W + (size_t)(k0 + r) * N + n0 + tc * 4);
        *(float4*)(&tile[r * 68 + tc * 4]) = v;
    }
    __syncthreads();
#pragma unroll
    for (int i = 0; i < 4; ++i) {
        int nl = tr + i * 16;
        h4 hv;
#pragma unroll
        for (int j = 0; j < 4; ++j)
            hv[j] = (_Float16)tile[(tc * 4 + j) * 68 + nl];
        *(h4*)(Wt + (size_t)(n0 + nl) * K + k0 + tc * 4) = hv;
    }
}

// ---------------- 128xBN MFMA GEMM, 2-phase double-buffered gload_lds ----------------
// Session-best sync structure (r8/r16/r18/r19 verified); BN=192 QKV (best total),
// BN=128 proj. MODE 0: scatter Q/K (B,H,T,64), V^T (B,H,64,T); Q pre-scaled
// 0.125*log2(e) (attention works in exp2 domain). MODE 1: fp32 out.
template <int BN, int MODE>
__global__ __launch_bounds__(256) void k_gemm(const _Float16* __restrict__ A,
                                              const _Float16* __restrict__ Bt,
                                              const float* __restrict__ bias,
                                              _Float16* __restrict__ oQ,
                                              _Float16* __restrict__ oK,
                                              _Float16* __restrict__ oV,
                                              float* __restrict__ oF,
                                              int M, int N, int K) {
    constexpr int BFR = BN / 32;          // B frag cols per wave
    constexpr int BSI = BN / 64;          // B stage instrs per wave
    __shared__ _Float16 As[2][128 * 32];  // linear [row][k], 64B rows
    __shared__ _Float16 Bs[2][BN * 32];
    const int tid = threadIdx.x;
    const int lane = tid & 63, wv = tid >> 6;
    const int wm = wv >> 1, wn = wv & 1;
    const int l15 = lane & 15, l4 = lane >> 4;
    const int bm = blockIdx.x * 128, bn = blockIdx.y * BN;
    f4 acc[4][BFR] = {};

    const int srow = lane >> 2, scol = (lane & 3) * 8;
    const _Float16* Ag = A + (size_t)(bm + srow) * K + scol;
    const _Float16* Bg = Bt + (size_t)(bn + srow) * K + scol;

#pragma unroll
    for (int j = 0; j < 2; ++j)
        gload16(Ag + (size_t)((wv * 2 + j) * 16) * K, &As[0][(wv * 2 + j) * 512]);
#pragma unroll
    for (int j = 0; j < BSI; ++j)
        gload16(Bg + (size_t)((wv * BSI + j) * 16) * K, &Bs[0][(wv * BSI + j) * 512]);
    asm volatile("s_waitcnt vmcnt(0)" ::: "memory");
    __syncthreads();

    int cur = 0;
    for (int k0 = 0; k0 < K; k0 += 32) {
        if (k0 + 32 < K) {
#pragma unroll
            for (int j = 0; j < 2; ++j)
                gload16(Ag + (size_t)((wv * 2 + j) * 16) * K + k0 + 32,
                        &As[cur ^ 1][(wv * 2 + j) * 512]);
#pragma unroll
            for (int j = 0; j < BSI; ++j)
                gload16(Bg + (size_t)((wv * BSI + j) * 16) * K + k0 + 32,
                        &Bs[cur ^ 1][(wv * BSI + j) * 512]);
        }

        const _Float16* Ac = As[cur];
        const _Float16* Bc = Bs[cur];
        h8 af[4], bf[BFR];
#pragma unroll
        for (int i = 0; i < 4; ++i)
            af[i] = *(const h8*)(&Ac[(wm * 64 + i * 16 + l15) * 32 + l4 * 8]);
#pragma unroll
        for (int i = 0; i < BFR; ++i)
            bf[i] = *(const h8*)(&Bc[(wn * (BN / 2) + i * 16 + l15) * 32 + l4 * 8]);
        __builtin_amdgcn_s_setprio(1);
#pragma unroll
        for (int mi = 0; mi < 4; ++mi)
#pragma unroll
            for (int ni = 0; ni < BFR; ++ni)
                acc[mi][ni] = MFMA16(af[mi], bf[ni], acc[mi][ni]);
        __builtin_amdgcn_s_setprio(0);

        asm volatile("s_waitcnt vmcnt(0)" ::: "memory");
        __syncthreads();
        cur ^= 1;
    }

#pragma unroll
    for (int mi = 0; mi < 4; ++mi) {
#pragma unroll
        for (int ni = 0; ni < BFR; ++ni) {
            int col = bn + wn * (BN / 2) + ni * 16 + l15;
            float bv = bias[col];
            int rb = bm + wm * 64 + mi * 16 + l4 * 4;
            if (MODE == 0) {
                int which = col >> 10, n1 = col & 1023;
                int hh = n1 >> 6, dd = n1 & 63;
                if (which == 2) {
                    int b = rb >> 11, tq = rb & 2047;
                    h4 pv;
#pragma unroll
                    for (int i = 0; i < 4; ++i) pv[i] = (_Float16)(acc[mi][ni][i] + bv);
                    *(h4*)(oV + ((size_t)(b * 16 + hh) * 64 + dd) * 2048 + tq) = pv;
                } else {
                    _Float16* dst = which == 0 ? oQ : oK;
                    const float scl = which == 0 ? 0.18033688011112042f : 1.0f; // 0.125*log2(e)
#pragma unroll
                    for (int i = 0; i < 4; ++i) {
                        int row = rb + i;
                        int b = row >> 11, tq = row & 2047;
                        dst[(((size_t)b * 16 + hh) * 2048 + tq) * 64 + dd] =
                            (_Float16)((acc[mi][ni][i] + bv) * scl);
                    }
                }
            } else {
#pragma unroll
                for (int i = 0; i < 4; ++i)
                    oF[(size_t)(rb + i) * N + col] = acc[mi][ni][i] + bv;
            }
        }
    }
}

// ---------------- causal flash attention: 4 waves x 32 q-rows, shared 64-key K/V tile ----------------
#define SWZI(row, cb) ((((row) << 7) + ((cb) ^ ((((row) & 7) << 4)))) >> 1)

__global__ __launch_bounds__(256) void k_attn(const _Float16* __restrict__ Qh,
                                              const _Float16* __restrict__ Kh,
                                              const _Float16* __restrict__ Vt,
                                              _Float16* __restrict__ Yh) {
    __shared__ _Float16 lds[8192];
    const int bid = blockIdx.x;
    const int bh = bid & 63;
    const int qt = 15 - (bid >> 6);
    const int tid = threadIdx.x, w = tid >> 6;
    const int l31 = tid & 31, hi = (tid >> 5) & 1;
    const int h16 = hi * 16, h4o = hi * 4;
    const size_t base = (size_t)bh * 2048 * 64;

    const int qabs = qt * 128 + w * 32 + l31;
    h8 qf[4];
#pragma unroll
    for (int dk = 0; dk < 4; ++dk)
        qf[dk] = *(const h8*)(Qh + base + (size_t)qabs * 64 + dk * 16 + hi * 8);

    f16x O0 = {}, O1 = {};
    float m = -1e30f, l = 0.f;

    const int sr = tid >> 3;
    const int sc8 = (tid & 7) * 8;
    const int scb = (tid & 7) * 16;
    const int kbb = 2 * qt + 1;
    const int kbw = 2 * qt + (w >> 1);

    {
#pragma unroll
        for (int j = 0; j < 2; ++j) {
            int row = j * 32 + sr;
            h8 kv = *(const h8*)(Kh + base + (size_t)row * 64 + sc8);
            h8 vv = *(const h8*)(Vt + base + (size_t)row * 2048 + sc8);
            *(h8*)(&lds[SWZI(row, scb)]) = kv;
            *(h8*)(&lds[4096 + SWZI(row, scb)]) = vv;
        }
    }
    __syncthreads();

    for (int kb = 0; kb <= kbb; ++kb) {
        const bool pre = (kb < kbb);
        h8 kn[2], vn[2];
        if (pre) {
#pragma unroll
            for (int j = 0; j < 2; ++j) {
                int row = j * 32 + sr;
                kn[j] = *(const h8*)(Kh + base + (size_t)((kb + 1) * 64 + row) * 64 + sc8);
                vn[j] = *(const h8*)(Vt + base + (size_t)row * 2048 + (kb + 1) * 64 + sc8);
            }
        }

        if (kb <= kbw) {
            f16x S0 = {}, S1 = {};
            __builtin_amdgcn_s_setprio(1);
#pragma unroll
            for (int dk = 0; dk < 4; ++dk) {
                h8 kf0 = *(const h8*)(&lds[SWZI(l31, dk * 32 + h16)]);
                h8 kf1 = *(const h8*)(&lds[SWZI(32 + l31, dk * 32 + h16)]);
                S0 = MFMA32(kf0, qf[dk], S0);
                S1 = MFMA32(kf1, qf[dk], S1);
            }
            __builtin_amdgcn_s_setprio(0);

            if (kb == kbw) {
#pragma unroll
                for (int r = 0; r < 16; ++r) {
                    int key = kb * 64 + (r & 3) + 8 * (r >> 2) + h4o;
                    if (key > qabs) S0[r] = -1e30f;
                    if (key + 32 > qabs) S1[r] = -1e30f;
                }
            }

            float tr[16];
#pragma unroll
            for (int r = 0; r < 16; ++r) tr[r] = fmaxf(S0[r], S1[r]);
#pragma unroll
            for (int st = 8; st >= 1; st >>= 1)
#pragma unroll
                for (int r = 0; r < st; ++r) tr[r] = fmaxf(tr[r], tr[r + st]);
            float pm = fmaxf(tr[0], swap_half(tr[0]));
            if (!__all(pm - m <= 8.f)) {
                float mnew = fmaxf(m, pm);
                float scl = __builtin_amdgcn_exp2f(m - mnew);
                m = mnew;
                l *= scl;
#pragma unroll
                for (int r = 0; r < 16; ++r) { O0[r] *= scl; O1[r] *= scl; }
            }
#pragma unroll
            for (int r = 0; r < 16; ++r) {
                S0[r] = __builtin_amdgcn_exp2f(S0[r] - m);
                S1[r] = __builtin_amdgcn_exp2f(S1[r] - m);
            }
#pragma unroll
            for (int r = 0; r < 16; ++r) tr[r] = S0[r] + S1[r];
#pragma unroll
            for (int st = 8; st >= 1; st >>= 1)
#pragma unroll
                for (int r = 0; r < st; ++r) tr[r] += tr[r + st];
            l += tr[0] + swap_half(tr[0]);

            h8 pb[4];
#pragma unroll
            for (int kk = 0; kk < 4; ++kk) {
                const int bb = (kk & 1) * 8;
                unsigned W0, W1, W2, W3;
                if (kk < 2) {
                    W0 = __builtin_bit_cast(unsigned, __builtin_amdgcn_cvt_pkrtz(S0[bb + 0], S0[bb + 1]));
                    W1 = __builtin_bit_cast(unsigned, __builtin_amdgcn_cvt_pkrtz(S0[bb + 2], S0[bb + 3]));
                    W2 = __builtin_bit_cast(unsigned, __builtin_amdgcn_cvt_pkrtz(S0[bb + 4], S0[bb + 5]));
                    W3 = __builtin_bit_cast(unsigned, __builtin_amdgcn_cvt_pkrtz(S0[bb + 6], S0[bb + 7]));
                } else {
                    W0 = __builtin_bit_cast(unsigned, __builtin_amdgcn_cvt_pkrtz(S1[bb + 0], S1[bb + 1]));
                    W1 = __builtin_bit_cast(unsigned, __builtin_amdgcn_cvt_pkrtz(S1[bb + 2], S1[bb + 3]));
                    W2 = __builtin_bit_cast(unsigned, __builtin_amdgcn_cvt_pkrtz(S1[bb + 4], S1[bb + 5]));
                    W3 = __builtin_bit_cast(unsigned, __builtin_amdgcn_cvt_pkrtz(S1[bb + 6], S1[bb + 7]));
                }
                unsigned E0 = (unsigned)__shfl_xor((int)(hi ? W0 : W2), 32, 64);
                unsigned E1 = (unsigned)__shfl_xor((int)(hi ? W1 : W3), 32, 64);
                u4 wvv;
                wvv[0] = hi ? E0 : W0;
                wvv[1] = hi ? E1 : W1;
                wvv[2] = hi ? W2 : E0;
                wvv[3] = hi ? W3 : E1;
                pb[kk] = __builtin_bit_cast(h8, wvv);
            }

            __builtin_amdgcn_s_setprio(1);
#pragma unroll
            for (int kk = 0; kk < 4; ++kk) {
                h8 vf0 = *(const h8*)(&lds[4096 + SWZI(l31, kk * 32 + h16)]);
                h8 vf1 = *(const h8*)(&lds[4096 + SWZI(32 + l31, kk * 32 + h16)]);
                O0 = MFMA32(vf0, pb[kk], O0);
                O1 = MFMA32(vf1, pb[kk], O1);
            }
            __builtin_amdgcn_s_setprio(0);
        }

        __syncthreads();
        if (pre) {
#pragma unroll
            for (int j = 0; j < 2; ++j) {
                int row = j * 32 + sr;
                *(h8*)(&lds[SWZI(row, scb)]) = kn[j];
                *(h8*)(&lds[4096 + SWZI(row, scb)]) = vn[j];
            }
            __syncthreads();
        }
    }

    __syncthreads();

    {
        float inv = 1.0f / l;
        const int R = w * 32 + l31;
#pragma unroll
        for (int rr = 0; rr < 4; ++rr) {
            h4 a, b;
#pragma unroll
            for (int q = 0; q < 4; ++q) {
                a[q] = (_Float16)(O0[rr * 4 + q] * inv);
                b[q] = (_Float16)(O1[rr * 4 + q] * inv);
            }
            *(h4*)(&lds[SWZI(R, rr * 16 + hi * 8)]) = a;
            *(h4*)(&lds[SWZI(R, 64 + rr * 16 + hi * 8)]) = b;
        }
    }
    __syncthreads();
    {
        const int b = bh >> 4, head = bh & 15;
        const int row = tid >> 1;
#pragma unroll
        for (int i = 0; i < 4; ++i) {
            int seg = (tid & 1) * 4 + i;
            h8 v = *(const h8*)(&lds[SWZI(row, seg * 16)]);
            *(h8*)(Yh + ((size_t)(b * 2048 + qt * 128 + row)) * 1024 + head * 64 + seg * 8) = v;
        }
    }
}

extern "C" void kernel_launch(void* const* d_in, const int* in_sizes, int n_in,
                              void* d_out, int out_size, void* d_ws, size_t ws_size,
                              hipStream_t stream) {
    const float* x  = (const float*)d_in[0];
    const float* Wa = (const float*)d_in[1];
    const float* ba = (const float*)d_in[2];
    const float* Wp = (const float*)d_in[3];
    const float* bp = (const float*)d_in[4];
    float* out = (float*)d_out;

    _Float16* ws = (_Float16*)d_ws;
    const size_t SZ_X = (size_t)8192 * 1024;
    const size_t SZ_WA = (size_t)3072 * 1024;
    const size_t SZ_WP = (size_t)1024 * 1024;
    const size_t SZ_H = (size_t)64 * 2048 * 64;
    _Float16* xh  = ws;
    _Float16* WaT = xh + SZ_X;
    _Float16* WpT = WaT + SZ_WA;
    _Float16* Qh  = WpT + SZ_WP;
    _Float16* Kh  = Qh + SZ_H;
    _Float16* Vth = Kh + SZ_H;    // V transposed: (bh, d, t)
    _Float16* Yh  = Vth + SZ_H;

    k_f32_to_f16<<<8192, 256, 0, stream>>>(x, xh, (int)(SZ_X / 4));
    k_transpose_both<<<dim3(16, 64), 256, 0, stream>>>(Wa, WaT, Wp, WpT);
    // QKV: 128x192 tiles -> grid 64x16 = 1024, no dispatch tail
    k_gemm<192, 0><<<dim3(64, 16), 256, 0, stream>>>(xh, WaT, ba, Qh, Kh, Vth, nullptr,
                                                     8192, 3072, 1024);
    k_attn<<<1024, 256, 0, stream>>>(Qh, Kh, Vth, Yh);
    k_gemm<128, 1><<<dim3(64, 8), 256, 0, stream>>>(Yh, WpT, bp, nullptr, nullptr, nullptr,
                                                    out, 8192, 1024, 1024);
}